// Round 4
// baseline (694.967 us; speedup 1.0000x reference)
//
#include <hip/hip_runtime.h>

#define BB 4
#define CC 64
#define HH 128
#define WW 128
#define NN (HH*WW)      // 16384
#define HP 130
#define NPP (HP*HP)     // 16900 (1-pad fields: K, V, r)
#define HP2 132
#define NPP2 (HP2*HP2)  // 17424 (2-pad field: Q)
#define NH 8
#define DD 72

// ---------------- K0: transpose w_proj [oc][ci][3][3] -> wt[ci][w][oc] ----------------
__global__ __launch_bounds__(256) void k0_wt(const float* __restrict__ wproj, float* __restrict__ wt){
    int idx = blockIdx.x*256 + threadIdx.x;      // 64*9*64 = 36864
    if (idx >= 64*9*64) return;
    int oc = idx & 63;
    int w  = (idx >> 6) % 9;
    int ci = idx / 576;
    wt[idx] = wproj[(oc*64 + ci)*9 + w];
}

// ---------------- K1: qkv = x @ w_qkv^T + b ; relu on q,k ; write padded fields -------
__global__ __launch_bounds__(256) void k1_qkv(const float* __restrict__ x,
        const float* __restrict__ wqkv, const float* __restrict__ bqkv,
        float* __restrict__ Qp, float* __restrict__ Kp, float* __restrict__ Vp){
    __shared__ float wl[64*68];   // [c][orel] stride 68
    __shared__ float bl[64];
    const int t = threadIdx.x;
    const int gy = blockIdx.y;    // 0=q,1=k,2=v
    const int b  = blockIdx.z;
    for (int k = 0; k < 16; ++k){
        int idx = t + k*256;               // 4096
        int orel = idx >> 6, c = idx & 63;
        wl[c*68 + orel] = wqkv[(gy*64 + orel)*64 + c];
    }
    if (t < 64) bl[t] = bqkv[gy*64 + t];
    __syncthreads();
    const int pix = blockIdx.x*256 + t;
    float acc[64];
#pragma unroll
    for (int o=0;o<64;++o) acc[o]=0.f;
    const float* xb = x + (size_t)(b*64)*NN + pix;
    for (int c=0;c<64;++c){
        float xv = xb[(size_t)c*NN];
        const float4* wrow = (const float4*)(&wl[c*68]);
#pragma unroll
        for (int o4=0;o4<16;++o4){
            float4 wv = wrow[o4];
            acc[o4*4+0] += xv*wv.x;
            acc[o4*4+1] += xv*wv.y;
            acc[o4*4+2] += xv*wv.z;
            acc[o4*4+3] += xv*wv.w;
        }
    }
    const int y = pix >> 7, xx = pix & 127;
    float* dst; size_t cstride;
    if (gy == 0){ dst = Qp + (size_t)(b*64)*NPP2 + (y+2)*HP2 + (xx+2); cstride = NPP2; }
    else { dst = ((gy==1)?Kp:Vp) + (size_t)(b*64)*NPP + (y+1)*HP + (xx+1); cstride = NPP; }
    const bool dorelu = (gy < 2);
#pragma unroll
    for (int o=0;o<64;++o){
        float v = acc[o] + bl[o];
        if (dorelu) v = fmaxf(v, 0.f);
        dst[(size_t)o*cstride] = v;
    }
}

// ---------------- K3: GEMM-style kv (+fused ksum): kvT2[e][cd*12+w] += K^T V ----------
// Block: (b,h, 4-image-row chunk). LDS-staged unfolded tiles [72][64px], 8x8 lane grid,
// 9x9 register tile per lane. 4-wave LDS reduce, then global atomicAdd into zeroed kvT2.
__global__ __launch_bounds__(256) void k3_kv(const float* __restrict__ Kp, const float* __restrict__ Vp,
                                             float* __restrict__ kvT2, float* __restrict__ ksum){
    __shared__ __align__(16) float lds[2*72*68];   // Kt | Vt ; reused as red[72*72]
    float* Kt = lds;
    float* Vt = lds + 72*68;
    const int t = threadIdx.x;
    const int h = blockIdx.y, b = blockIdx.z;
    const int y0 = blockIdx.x * 4;            // 4 image rows per block
    const int bh = b*NH + h;
    const float* Kb = Kp + (size_t)(b*64 + h*8)*NPP;
    const float* Vb = Vp + (size_t)(b*64 + h*8)*NPP;

    // staging offsets: thread t stages rows d = (t>>6)+4k, pixel p = t&63
    const int p  = t & 63;
    const int d0 = t >> 6;
    const int lbase = d0*68 + p;
    int ofs[18];
#pragma unroll
    for (int k=0;k<18;++k){
        int d = d0 + 4*k;
        int cl = d/9, w = d - 9*cl, wi = w/3, wj = w - 3*wi;
        ofs[k] = cl*NPP + wi*HP + wj + p;
    }

    const int l  = t & 63;
    const int i9 = (l >> 3) * 9;     // d-tile base
    const int j9 = (l & 7) * 9;      // e-tile base
    const bool ks_lane = ((l & 7) == 0);

    float acc[9][9];
#pragma unroll
    for (int a=0;a<9;++a)
#pragma unroll
        for (int c=0;c<9;++c) acc[a][c]=0.f;
    float ksa[9];
#pragma unroll
    for (int a=0;a<9;++a) ksa[a]=0.f;

    for (int r = 0; r < 8; ++r){      // 8 rounds of 64 pixels (half image row)
        const int y  = y0 + (r >> 1);
        const int x0 = (r & 1) * 64;
        const int gof = y*HP + x0;
        __syncthreads();
#pragma unroll
        for (int k=0;k<18;++k){
            Kt[lbase + 272*k] = Kb[ofs[k] + gof];
            Vt[lbase + 272*k] = Vb[ofs[k] + gof];
        }
        __syncthreads();
        const int p0 = (t >> 6) * 16;   // wave's 16-pixel subset
#pragma unroll
        for (int g=0; g<4; ++g){
            float4 kf[9];
            const float* kb2 = &Kt[i9*68 + p0 + 4*g];
#pragma unroll
            for (int a=0;a<9;++a) kf[a] = *(const float4*)(kb2 + a*68);
            if (ks_lane){
#pragma unroll
                for (int a=0;a<9;++a) ksa[a] += kf[a].x+kf[a].y+kf[a].z+kf[a].w;
            }
            const float* vb2 = &Vt[j9*68 + p0 + 4*g];
#pragma unroll
            for (int c3=0;c3<3;++c3){
                float4 vf[3];
#pragma unroll
                for (int cc=0;cc<3;++cc) vf[cc] = *(const float4*)(vb2 + (c3*3+cc)*68);
#pragma unroll
                for (int a=0;a<9;++a)
#pragma unroll
                    for (int cc=0;cc<3;++cc){
                        acc[a][c3*3+cc] += kf[a].x*vf[cc].x + kf[a].y*vf[cc].y
                                         + kf[a].z*vf[cc].z + kf[a].w*vf[cc].w;
                    }
            }
        }
    }
    // block-level reduce of the 4 wave-copies via LDS (reuse staging buffer)
    __syncthreads();
    const int wv = t >> 6;
    for (int turn=0; turn<4; ++turn){
        if (wv == turn){
#pragma unroll
            for (int a=0;a<9;++a)
#pragma unroll
                for (int c=0;c<9;++c){
                    float* cell = &lds[(i9+a)*72 + (j9+c)];
                    if (turn == 0) *cell = acc[a][c];
                    else           *cell += acc[a][c];
                }
        }
        __syncthreads();
    }
    // flush partial kv to global (zero-initialized kvT2), 32 chunks add per cell
    float* kvdst = kvT2 + (size_t)bh*DD*96;
    for (int idx=t; idx<72*72; idx+=256){
        int e = idx / 72, d = idx - e*72;
        int cd = d / 9, w = d - cd*9;
        atomicAdd(&kvdst[e*96 + cd*12 + w], lds[d*72 + e]);
    }
    if (ks_lane){
        float* kd = ksum + (size_t)bh*DD;
#pragma unroll
        for (int a=0;a<9;++a) atomicAdd(&kd[i9+a], ksa[a]);
    }
}

// ---------------- K4: r[b][h][pad(y,x)] = 1/(q . ksum + eps), zero-padded 130x130 -----
__global__ __launch_bounds__(256) void k4_r(const float* __restrict__ Qp, const float* __restrict__ ksum,
                                            float* __restrict__ rfp){
    const int h = blockIdx.y, b = blockIdx.z;
    __shared__ float ks[72];
    if (threadIdx.x < 72) ks[threadIdx.x] = ksum[(b*NH + h)*DD + threadIdx.x];
    __syncthreads();
    const int pix = blockIdx.x*256 + threadIdx.x;
    const int y = pix >> 7, xx = pix & 127;
    const float* Qb = Qp + (size_t)(b*64 + h*8)*NPP2 + (y+1)*HP2 + (xx+1);
    float denom = 0.f;
#pragma unroll
    for (int cl=0; cl<8; ++cl){
        const float* q = Qb + (size_t)cl*NPP2;
#pragma unroll
        for (int w=0; w<9; ++w){
            denom += q[(w/3)*HP2 + (w%3)] * ks[cl*9 + w];
        }
    }
    rfp[(size_t)(b*NH + h)*NPP + (y+1)*HP + (xx+1)] = 1.f/(denom + 1e-6f);
}

// ---------------- K5: fused numerator + fold, wave-per-channel, kv via scalar loads ---
__global__ __launch_bounds__(512) void k5_attn(const float* __restrict__ Qp, const float* __restrict__ kvT2,
          const float* __restrict__ rfp, float* __restrict__ folded){
    __shared__ __align__(16) float Qt[8*20*20];   // [cl][20 rows][20 cols], origin (ty0-2,tx0-2)
    __shared__ __align__(16) float rt[18*20];     // [18 rows][stride 20], origin (ty0-1,tx0-1)
    const int t = threadIdx.x;
    const int tile = blockIdx.x;    // 8x8 tiles of 16x16
    const int h = blockIdx.y, b = blockIdx.z;
    const int ty0 = (tile >> 3)*16, tx0 = (tile & 7)*16;

    const float* Qb = Qp + (size_t)(b*64 + h*8)*NPP2 + (size_t)ty0*HP2 + tx0;
    for (int idx=t; idx<8*20*20; idx+=512){
        int cl = idx / 400; int rem = idx - cl*400; int r = rem/20, cc = rem - r*20;
        Qt[idx] = Qb[(size_t)cl*NPP2 + r*HP2 + cc];
    }
    const float* rg = rfp + (size_t)(b*NH + h)*NPP + (size_t)ty0*HP + tx0;
    for (int idx=t; idx<18*18; idx+=512){
        int rr = idx / 18, cc = idx - rr*18;
        rt[rr*20 + cc] = rg[rr*HP + cc];
    }
    __syncthreads();

    const int c  = __builtin_amdgcn_readfirstlane(t >> 6);  // wave-uniform channel
    const int l  = t & 63;
    const int pr = l >> 2;          // pixel row 0..15
    const int pc = (l & 3) * 4;     // pixel col start 0,4,8,12

    const float* kvc = kvT2 + ((size_t)(b*NH + h)*DD + c*9)*96;  // rows u=0..8, stride 96

    float acc[9][4];
#pragma unroll
    for (int u=0;u<9;++u)
#pragma unroll
        for (int p=0;p<4;++p) acc[u][p]=0.f;

    for (int cl=0; cl<8; ++cl){
        float qw[5][8];
        const float* qb = &Qt[cl*400 + pr*20 + pc];
#pragma unroll
        for (int rr=0; rr<5; ++rr){
            float4 a0 = *(const float4*)(qb + rr*20);
            float4 a1 = *(const float4*)(qb + rr*20 + 4);
            qw[rr][0]=a0.x; qw[rr][1]=a0.y; qw[rr][2]=a0.z; qw[rr][3]=a0.w;
            qw[rr][4]=a1.x; qw[rr][5]=a1.y; qw[rr][6]=a1.z; qw[rr][7]=a1.w;
        }
#pragma unroll
        for (int u=0; u<9; ++u){
            const float* kr = kvc + u*96 + cl*12;   // wave-uniform address
            float kw[9];
#pragma unroll
            for (int i=0;i<9;++i) kw[i] = kr[i];
            const int iu = u/3, ju = u - iu*3;
#pragma unroll
            for (int w=0; w<9; ++w){
                const int rr = (w/3) - iu + 2;
                const int cc = (w%3) - ju + 2;
#pragma unroll
                for (int p=0;p<4;++p)
                    acc[u][p] += qw[rr][cc+p] * kw[w];
            }
        }
    }
    float rw[3][6];
    const float* rb = &rt[pr*20 + pc];
#pragma unroll
    for (int rr=0; rr<3; ++rr)
#pragma unroll
        for (int j=0; j<6; ++j) rw[rr][j] = rb[rr*20 + j];
    float out[4];
#pragma unroll
    for (int p=0;p<4;++p) out[p]=0.f;
#pragma unroll
    for (int u=0; u<9; ++u){
        const int iu = u/3, ju = u - iu*3;
#pragma unroll
        for (int p=0;p<4;++p)
            out[p] += acc[u][p] * rw[2-iu][p+2-ju];
    }
    float4 o4 = make_float4(out[0], out[1], out[2], out[3]);
    *(float4*)(&folded[(size_t)(b*64 + h*8 + c)*NN + (ty0+pr)*WW + tx0 + pc]) = o4;
}

// ---------------- K6: y = conv3x3(folded/counts, w_proj) + b_proj ---------------------
__global__ __launch_bounds__(256) void k6_conv(const float* __restrict__ folded, const float* __restrict__ wt,
         const float* __restrict__ bproj, float* __restrict__ out){
    __shared__ __align__(16) float ut[8*18*12];   // [cil][rr(18)][cc(10), stride 12]
    const int t = threadIdx.x;
    const int tile = blockIdx.x;    // 0..127 : 8 row-tiles (16) x 16 col-tiles (8)
    const int b = blockIdx.y;
    const int ty0 = (tile >> 4)*16, tx0 = (tile & 15)*8;
    const int ocb = t & 15;         // 4 output channels
    const int s   = t >> 4;         // row 0..15
    float acc[4][8];
#pragma unroll
    for (int ol=0;ol<4;++ol)
#pragma unroll
        for (int p=0;p<8;++p) acc[ol][p]=0.f;
    const float4 bias = *(const float4*)(&bproj[ocb*4]);

    for (int ch=0; ch<8; ++ch){     // ci chunks of 8
        __syncthreads();
        for (int idx=t; idx<8*18*10; idx+=256){
            int cil = idx / 180; int rem = idx - cil*180; int rr = rem/10, cc = rem - rr*10;
            int iy = ty0 - 1 + rr, ix = tx0 - 1 + cc;
            float v = 0.f;
            if ((unsigned)iy < 128u && (unsigned)ix < 128u){
                int ry = 3 - (iy==0) - (iy==127);
                int rx = 3 - (ix==0) - (ix==127);
                v = folded[(size_t)(b*64 + ch*8 + cil)*NN + iy*WW + ix] / (float)(ry*rx);
            }
            ut[cil*216 + rr*12 + cc] = v;
        }
        __syncthreads();
        for (int cil=0; cil<8; ++cil){
            const int ci = ch*8 + cil;
            float uw[3][10];
            const float* ub = &ut[cil*216 + s*12];
#pragma unroll
            for (int dy=0;dy<3;++dy){
                float4 a0 = *(const float4*)(ub + dy*12);
                float4 a1 = *(const float4*)(ub + dy*12 + 4);
                float2 a2 = *(const float2*)(ub + dy*12 + 8);
                uw[dy][0]=a0.x; uw[dy][1]=a0.y; uw[dy][2]=a0.z; uw[dy][3]=a0.w;
                uw[dy][4]=a1.x; uw[dy][5]=a1.y; uw[dy][6]=a1.z; uw[dy][7]=a1.w;
                uw[dy][8]=a2.x; uw[dy][9]=a2.y;
            }
#pragma unroll
            for (int w=0;w<9;++w){
                const int dy = w/3, dx = w%3;
                float4 wv = *(const float4*)(&wt[(ci*9 + w)*64 + ocb*4]);
#pragma unroll
                for (int p=0;p<8;++p){
                    float u = uw[dy][p+dx];
                    acc[0][p] += wv.x*u;
                    acc[1][p] += wv.y*u;
                    acc[2][p] += wv.z*u;
                    acc[3][p] += wv.w*u;
                }
            }
        }
    }
    const int y = ty0 + s;
#pragma unroll
    for (int ol=0;ol<4;++ol){
        const int oc = ocb*4 + ol;
        float* dst = &out[(size_t)(b*64 + oc)*NN + y*WW + tx0];
        float bv = (ol==0)?bias.x:(ol==1)?bias.y:(ol==2)?bias.z:bias.w;
#pragma unroll
        for (int p=0;p<8;++p) dst[p] = acc[ol][p] + bv;
    }
}

extern "C" void kernel_launch(void* const* d_in, const int* in_sizes, int n_in,
                              void* d_out, int out_size, void* d_ws, size_t ws_size,
                              hipStream_t stream) {
    const float* x     = (const float*)d_in[0];
    const float* wqkv  = (const float*)d_in[1];
    const float* bqkv  = (const float*)d_in[2];
    const float* wproj = (const float*)d_in[3];
    const float* bproj = (const float*)d_in[4];
    float* out = (float*)d_out;
    float* ws  = (float*)d_ws;

    const size_t szQ2 = (size_t)BB*CC*NPP2;      // 4,460,544 floats (2-pad Q)
    const size_t szF  = (size_t)BB*CC*NPP;       // 4,326,400 floats (1-pad K/V)
    const size_t szR  = (size_t)BB*NH*NPP;       // 540,800 floats (1-pad r)
    const size_t szKV = (size_t)BB*NH*DD*96;     // 221,184 floats (kvT2, atomic target)
    const size_t szKS = (size_t)BB*NH*DD;        // 2,304 floats (ksum, atomic target)
    float* Qp2    = ws;
    float* Kp     = Qp2 + szQ2;
    float* Vp     = Kp + szF;
    float* rfp    = Vp + szF;
    float* kvT2   = rfp + szR;
    float* ksum   = kvT2 + szKV;
    float* folded = ksum + szKS;                 // B*C*N (written exclusively)
    float* wt     = folded + (size_t)BB*CC*NN;   // 64*9*64
    // total ~18.1M floats = ~72.4 MB of ws

    // zero the zero-padded fields + atomic accumulators (contiguous prefix)
    hipMemsetAsync(ws, 0, (szQ2 + 2*szF + szR + szKV + szKS)*sizeof(float), stream);

    k0_wt  <<<dim3(144),      256, 0, stream>>>(wproj, wt);
    k1_qkv <<<dim3(64, 3, 4), 256, 0, stream>>>(x, wqkv, bqkv, Qp2, Kp, Vp);
    k3_kv  <<<dim3(32, 8, 4), 256, 0, stream>>>(Kp, Vp, kvT2, ksum);
    k4_r   <<<dim3(64, 8, 4), 256, 0, stream>>>(Qp2, ksum, rfp);
    k5_attn<<<dim3(64, 8, 4), 512, 0, stream>>>(Qp2, kvT2, rfp, folded);
    k6_conv<<<dim3(128, 4),   256, 0, stream>>>(folded, wt, bproj, out);
}

// Round 5
// 429.743 us; speedup vs baseline: 1.6172x; 1.6172x over previous
//
#include <hip/hip_runtime.h>

#define BB 4
#define CC 64
#define HH 128
#define WW 128
#define NN (HH*WW)      // 16384
#define HP 130
#define NPP (HP*HP)     // 16900 (1-pad field: r)
#define HPS 132
#define NPPS (130*HPS)  // 17160 (1-pad K/V fields, 132-stride rows for aligned float4)
#define HP2 132
#define NPP2 (HP2*HP2)  // 17424 (2-pad field: Q)
#define NH 8
#define DD 72

// ---------------- K0: transpose w_proj [oc][ci][3][3] -> wt[ci][w][oc] ----------------
__global__ __launch_bounds__(256) void k0_wt(const float* __restrict__ wproj, float* __restrict__ wt){
    int idx = blockIdx.x*256 + threadIdx.x;      // 64*9*64 = 36864
    if (idx >= 64*9*64) return;
    int oc = idx & 63;
    int w  = (idx >> 6) % 9;
    int ci = idx / 576;
    wt[idx] = wproj[(oc*64 + ci)*9 + w];
}

// ---------------- K1: qkv = x @ w_qkv^T + b ; relu on q,k ; write padded fields -------
__global__ __launch_bounds__(256) void k1_qkv(const float* __restrict__ x,
        const float* __restrict__ wqkv, const float* __restrict__ bqkv,
        float* __restrict__ Qp, float* __restrict__ Kp, float* __restrict__ Vp){
    __shared__ float wl[64*68];   // [c][orel] stride 68
    __shared__ float bl[64];
    const int t = threadIdx.x;
    const int gy = blockIdx.y;    // 0=q,1=k,2=v
    const int b  = blockIdx.z;
    for (int k = 0; k < 16; ++k){
        int idx = t + k*256;               // 4096
        int orel = idx >> 6, c = idx & 63;
        wl[c*68 + orel] = wqkv[(gy*64 + orel)*64 + c];
    }
    if (t < 64) bl[t] = bqkv[gy*64 + t];
    __syncthreads();
    const int pix = blockIdx.x*256 + t;
    float acc[64];
#pragma unroll
    for (int o=0;o<64;++o) acc[o]=0.f;
    const float* xb = x + (size_t)(b*64)*NN + pix;
    for (int c=0;c<64;++c){
        float xv = xb[(size_t)c*NN];
        const float4* wrow = (const float4*)(&wl[c*68]);
#pragma unroll
        for (int o4=0;o4<16;++o4){
            float4 wv = wrow[o4];
            acc[o4*4+0] += xv*wv.x;
            acc[o4*4+1] += xv*wv.y;
            acc[o4*4+2] += xv*wv.z;
            acc[o4*4+3] += xv*wv.w;
        }
    }
    const int y = pix >> 7, xx = pix & 127;
    float* dst; size_t cstride;
    if (gy == 0){ dst = Qp + (size_t)(b*64)*NPP2 + (y+2)*HP2 + (xx+2); cstride = NPP2; }
    else { dst = ((gy==1)?Kp:Vp) + (size_t)(b*64)*NPPS + (y+1)*HPS + (xx+1); cstride = NPPS; }
    const bool dorelu = (gy < 2);
#pragma unroll
    for (int o=0;o<64;++o){
        float v = acc[o] + bl[o];
        if (dorelu) v = fmaxf(v, 0.f);
        dst[(size_t)o*cstride] = v;
    }
}

// ---------------- K2: ksum[b][h][cl*9+w] = windowed sums of Kpad ----------------------
__global__ __launch_bounds__(256) void k2_ksum(const float* __restrict__ Kp, float* __restrict__ ksum){
    const int c = blockIdx.x, b = blockIdx.y;
    const float* src = Kp + (size_t)(b*64 + c)*NPPS;
    float a[3][3];
#pragma unroll
    for (int i=0;i<3;++i)
#pragma unroll
        for (int j=0;j<3;++j) a[i][j]=0.f;
    for (int idx = threadIdx.x; idx < NPPS; idx += 256){
        int r = idx / HPS, cc = idx - r*HPS;
        float v = src[idx];
#pragma unroll
        for (int i=0;i<3;++i){
            bool fy = (unsigned)(r - i) < 128u;
#pragma unroll
            for (int j=0;j<3;++j){
                bool fx = (unsigned)(cc - j) < 128u;
                if (fy && fx) a[i][j] += v;
            }
        }
    }
    __shared__ float red[4][9];
#pragma unroll
    for (int i=0;i<3;++i)
#pragma unroll
        for (int j=0;j<3;++j){
            float v = a[i][j];
            for (int m=1;m<64;m<<=1) v += __shfl_xor(v, m, 64);
            a[i][j] = v;
        }
    int wave = threadIdx.x >> 6, lane = threadIdx.x & 63;
    if (lane == 0){
#pragma unroll
        for (int w=0;w<9;++w) red[wave][w] = a[w/3][w%3];
    }
    __syncthreads();
    if (threadIdx.x < 9){
        float s = red[0][threadIdx.x]+red[1][threadIdx.x]+red[2][threadIdx.x]+red[3][threadIdx.x];
        int h = c >> 3, cl = c & 7;
        ksum[(b*NH + h)*DD + cl*9 + threadIdx.x] = s;
    }
}

// ---------------- K3: kvT2[e][cd*12+w] = sum_n Kunf[cd*9+w,n] * Vunf[e,n] -------------
// Round-3 structure (direct global reads, shuffle reduce) but each thread owns a 1x4
// pixel strip: 12 aligned float4 loads feed 324 FMAs (6x VMEM-issue cut vs scalar).
__global__ __launch_bounds__(256) void k3_kv(const float* __restrict__ Kp, const float* __restrict__ Vp,
                                             float* __restrict__ kvT2){
    const int cc2 = blockIdx.x;          // cd*8+ce
    const int cd = cc2 >> 3, ce = cc2 & 7;
    const int h = blockIdx.y, b = blockIdx.z;
    const float* Kc = Kp + (size_t)(b*64 + h*8 + cd)*NPPS;
    const float* Vc = Vp + (size_t)(b*64 + h*8 + ce)*NPPS;
    const int x0 = (threadIdx.x & 31) * 4;    // image col group (4 px)
    const int yb = threadIdx.x >> 5;          // row slice 0..7
    float acc[9][9];
#pragma unroll
    for (int i=0;i<9;++i)
#pragma unroll
        for (int j=0;j<9;++j) acc[i][j]=0.f;

    for (int it=0; it<16; ++it){
        const int y = it*8 + yb;              // image row; window = padded rows y..y+2
        const float* kb = Kc + y*HPS + x0;
        const float* vb = Vc + y*HPS + x0;
        float kr[3][8], vr[3][8];
#pragma unroll
        for (int rr=0; rr<3; ++rr){
            float4 a0 = *(const float4*)(kb + rr*HPS);
            float4 a1 = *(const float4*)(kb + rr*HPS + 4);
            kr[rr][0]=a0.x; kr[rr][1]=a0.y; kr[rr][2]=a0.z; kr[rr][3]=a0.w;
            kr[rr][4]=a1.x; kr[rr][5]=a1.y; kr[rr][6]=a1.z; kr[rr][7]=a1.w;
            float4 b0 = *(const float4*)(vb + rr*HPS);
            float4 b1 = *(const float4*)(vb + rr*HPS + 4);
            vr[rr][0]=b0.x; vr[rr][1]=b0.y; vr[rr][2]=b0.z; vr[rr][3]=b0.w;
            vr[rr][4]=b1.x; vr[rr][5]=b1.y; vr[rr][6]=b1.z; vr[rr][7]=b1.w;
        }
#pragma unroll
        for (int p=0; p<4; ++p){
#pragma unroll
            for (int w=0; w<9; ++w){
                const float kv_ = kr[w/3][p + (w%3)];
#pragma unroll
                for (int w2=0; w2<9; ++w2)
                    acc[w][w2] += kv_ * vr[w2/3][p + (w2%3)];
            }
        }
    }
    __shared__ float red[4][81];
#pragma unroll
    for (int w=0;w<9;++w)
#pragma unroll
        for (int w2=0;w2<9;++w2){
            float v = acc[w][w2];
            for (int m=1;m<64;m<<=1) v += __shfl_xor(v, m, 64);
            acc[w][w2] = v;
        }
    int wave = threadIdx.x >> 6, lane = threadIdx.x & 63;
    if (lane == 0){
#pragma unroll
        for (int w=0;w<9;++w)
#pragma unroll
            for (int w2=0;w2<9;++w2) red[wave][w*9+w2] = acc[w][w2];
    }
    __syncthreads();
    if (threadIdx.x < 81){
        float s = red[0][threadIdx.x]+red[1][threadIdx.x]+red[2][threadIdx.x]+red[3][threadIdx.x];
        int w = threadIdx.x / 9, w2 = threadIdx.x - w*9;   // d = cd*9+w, e = ce*9+w2
        kvT2[((size_t)(b*NH + h)*DD + ce*9 + w2)*96 + cd*12 + w] = s;
    }
}

// ---------------- K4: r[b][h][pad(y,x)] = 1/(q . ksum + eps), zero-padded 130x130 -----
__global__ __launch_bounds__(256) void k4_r(const float* __restrict__ Qp, const float* __restrict__ ksum,
                                            float* __restrict__ rfp){
    const int h = blockIdx.y, b = blockIdx.z;
    __shared__ float ks[72];
    if (threadIdx.x < 72) ks[threadIdx.x] = ksum[(b*NH + h)*DD + threadIdx.x];
    __syncthreads();
    const int pix = blockIdx.x*256 + threadIdx.x;
    const int y = pix >> 7, xx = pix & 127;
    const float* Qb = Qp + (size_t)(b*64 + h*8)*NPP2 + (y+1)*HP2 + (xx+1);
    float denom = 0.f;
#pragma unroll
    for (int cl=0; cl<8; ++cl){
        const float* q = Qb + (size_t)cl*NPP2;
#pragma unroll
        for (int w=0; w<9; ++w){
            denom += q[(w/3)*HP2 + (w%3)] * ks[cl*9 + w];
        }
    }
    rfp[(size_t)(b*NH + h)*NPP + (y+1)*HP + (xx+1)] = 1.f/(denom + 1e-6f);
}

// ---------------- K5: fused numerator + fold, wave-per-channel, kv via scalar loads ---
__global__ __launch_bounds__(512) void k5_attn(const float* __restrict__ Qp, const float* __restrict__ kvT2,
          const float* __restrict__ rfp, float* __restrict__ folded){
    __shared__ __align__(16) float Qt[8*20*20];   // [cl][20 rows][20 cols], origin (ty0-2,tx0-2)
    __shared__ __align__(16) float rt[18*20];     // [18 rows][stride 20], origin (ty0-1,tx0-1)
    const int t = threadIdx.x;
    const int tile = blockIdx.x;    // 8x8 tiles of 16x16
    const int h = blockIdx.y, b = blockIdx.z;
    const int ty0 = (tile >> 3)*16, tx0 = (tile & 7)*16;

    const float* Qb = Qp + (size_t)(b*64 + h*8)*NPP2 + (size_t)ty0*HP2 + tx0;
    for (int idx=t; idx<8*20*20; idx+=512){
        int cl = idx / 400; int rem = idx - cl*400; int r = rem/20, cc = rem - r*20;
        Qt[idx] = Qb[(size_t)cl*NPP2 + r*HP2 + cc];
    }
    const float* rg = rfp + (size_t)(b*NH + h)*NPP + (size_t)ty0*HP + tx0;
    for (int idx=t; idx<18*18; idx+=512){
        int rr = idx / 18, cc = idx - rr*18;
        rt[rr*20 + cc] = rg[rr*HP + cc];
    }
    __syncthreads();

    const int c  = __builtin_amdgcn_readfirstlane(t >> 6);  // wave-uniform channel
    const int l  = t & 63;
    const int pr = l >> 2;          // pixel row 0..15
    const int pc = (l & 3) * 4;     // pixel col start 0,4,8,12

    const float* kvc = kvT2 + ((size_t)(b*NH + h)*DD + c*9)*96;  // rows u=0..8, stride 96

    float acc[9][4];
#pragma unroll
    for (int u=0;u<9;++u)
#pragma unroll
        for (int p=0;p<4;++p) acc[u][p]=0.f;

    for (int cl=0; cl<8; ++cl){
        float qw[5][8];
        const float* qb = &Qt[cl*400 + pr*20 + pc];
#pragma unroll
        for (int rr=0; rr<5; ++rr){
            float4 a0 = *(const float4*)(qb + rr*20);
            float4 a1 = *(const float4*)(qb + rr*20 + 4);
            qw[rr][0]=a0.x; qw[rr][1]=a0.y; qw[rr][2]=a0.z; qw[rr][3]=a0.w;
            qw[rr][4]=a1.x; qw[rr][5]=a1.y; qw[rr][6]=a1.z; qw[rr][7]=a1.w;
        }
#pragma unroll
        for (int u=0; u<9; ++u){
            const float* kr = kvc + u*96 + cl*12;   // wave-uniform address
            float kw[9];
#pragma unroll
            for (int i=0;i<9;++i) kw[i] = kr[i];
            const int iu = u/3, ju = u - iu*3;
#pragma unroll
            for (int w=0; w<9; ++w){
                const int rr = (w/3) - iu + 2;
                const int cc = (w%3) - ju + 2;
#pragma unroll
                for (int p=0;p<4;++p)
                    acc[u][p] += qw[rr][cc+p] * kw[w];
            }
        }
    }
    float rw[3][6];
    const float* rb = &rt[pr*20 + pc];
#pragma unroll
    for (int rr=0; rr<3; ++rr)
#pragma unroll
        for (int j=0; j<6; ++j) rw[rr][j] = rb[rr*20 + j];
    float out[4];
#pragma unroll
    for (int p=0;p<4;++p) out[p]=0.f;
#pragma unroll
    for (int u=0; u<9; ++u){
        const int iu = u/3, ju = u - iu*3;
#pragma unroll
        for (int p=0;p<4;++p)
            out[p] += acc[u][p] * rw[2-iu][p+2-ju];
    }
    float4 o4 = make_float4(out[0], out[1], out[2], out[3]);
    *(float4*)(&folded[(size_t)(b*64 + h*8 + c)*NN + (ty0+pr)*WW + tx0 + pc]) = o4;
}

// ---------------- K6: y = conv3x3(folded/counts, w_proj) + b_proj ---------------------
__global__ __launch_bounds__(256) void k6_conv(const float* __restrict__ folded, const float* __restrict__ wt,
         const float* __restrict__ bproj, float* __restrict__ out){
    __shared__ __align__(16) float ut[8*18*12];   // [cil][rr(18)][cc(10), stride 12]
    const int t = threadIdx.x;
    const int tile = blockIdx.x;    // 0..127 : 8 row-tiles (16) x 16 col-tiles (8)
    const int b = blockIdx.y;
    const int ty0 = (tile >> 4)*16, tx0 = (tile & 15)*8;
    const int ocb = t & 15;         // 4 output channels
    const int s   = t >> 4;         // row 0..15
    float acc[4][8];
#pragma unroll
    for (int ol=0;ol<4;++ol)
#pragma unroll
        for (int p=0;p<8;++p) acc[ol][p]=0.f;
    const float4 bias = *(const float4*)(&bproj[ocb*4]);

    for (int ch=0; ch<8; ++ch){     // ci chunks of 8
        __syncthreads();
        for (int idx=t; idx<8*18*10; idx+=256){
            int cil = idx / 180; int rem = idx - cil*180; int rr = rem/10, cc = rem - rr*10;
            int iy = ty0 - 1 + rr, ix = tx0 - 1 + cc;
            float v = 0.f;
            if ((unsigned)iy < 128u && (unsigned)ix < 128u){
                int ry = 3 - (iy==0) - (iy==127);
                int rx = 3 - (ix==0) - (ix==127);
                v = folded[(size_t)(b*64 + ch*8 + cil)*NN + iy*WW + ix] / (float)(ry*rx);
            }
            ut[cil*216 + rr*12 + cc] = v;
        }
        __syncthreads();
        for (int cil=0; cil<8; ++cil){
            const int ci = ch*8 + cil;
            float uw[3][10];
            const float* ub = &ut[cil*216 + s*12];
#pragma unroll
            for (int dy=0;dy<3;++dy){
                float4 a0 = *(const float4*)(ub + dy*12);
                float4 a1 = *(const float4*)(ub + dy*12 + 4);
                float2 a2 = *(const float2*)(ub + dy*12 + 8);
                uw[dy][0]=a0.x; uw[dy][1]=a0.y; uw[dy][2]=a0.z; uw[dy][3]=a0.w;
                uw[dy][4]=a1.x; uw[dy][5]=a1.y; uw[dy][6]=a1.z; uw[dy][7]=a1.w;
                uw[dy][8]=a2.x; uw[dy][9]=a2.y;
            }
#pragma unroll
            for (int w=0;w<9;++w){
                const int dy = w/3, dx = w%3;
                float4 wv = *(const float4*)(&wt[(ci*9 + w)*64 + ocb*4]);
#pragma unroll
                for (int p=0;p<8;++p){
                    float u = uw[dy][p+dx];
                    acc[0][p] += wv.x*u;
                    acc[1][p] += wv.y*u;
                    acc[2][p] += wv.z*u;
                    acc[3][p] += wv.w*u;
                }
            }
        }
    }
    const int y = ty0 + s;
#pragma unroll
    for (int ol=0;ol<4;++ol){
        const int oc = ocb*4 + ol;
        float* dst = &out[(size_t)(b*64 + oc)*NN + y*WW + tx0];
        float bv = (ol==0)?bias.x:(ol==1)?bias.y:(ol==2)?bias.z:bias.w;
#pragma unroll
        for (int p=0;p<8;++p) dst[p] = acc[ol][p] + bv;
    }
}

extern "C" void kernel_launch(void* const* d_in, const int* in_sizes, int n_in,
                              void* d_out, int out_size, void* d_ws, size_t ws_size,
                              hipStream_t stream) {
    const float* x     = (const float*)d_in[0];
    const float* wqkv  = (const float*)d_in[1];
    const float* bqkv  = (const float*)d_in[2];
    const float* wproj = (const float*)d_in[3];
    const float* bproj = (const float*)d_in[4];
    float* out = (float*)d_out;
    float* ws  = (float*)d_ws;

    const size_t szQ2 = (size_t)BB*CC*NPP2;      // 4,460,544 floats (2-pad Q)
    const size_t szFS = (size_t)BB*CC*NPPS;      // 4,392,960 floats (132-stride K/V)
    const size_t szR  = (size_t)BB*NH*NPP;       // 540,800 floats (1-pad r)
    const size_t szKV = (size_t)BB*NH*DD*96;     // 221,184 floats (kvT2, exclusive writes)
    const size_t szKS = (size_t)BB*NH*DD;        // 2,304 floats (ksum, exclusive writes)
    float* Qp2    = ws;
    float* Kp     = Qp2 + szQ2;
    float* Vp     = Kp + szFS;
    float* rfp    = Vp + szFS;
    float* kvT2   = rfp + szR;
    float* ksum   = kvT2 + szKV;
    float* folded = ksum + szKS;                 // B*C*N (written exclusively)
    float* wt     = folded + (size_t)BB*CC*NN;   // 64*9*64
    // total ~18.2M floats = ~72.9 MB of ws

    // zero only the zero-padded fields (contiguous prefix): Qp2, Kp, Vp, rfp
    hipMemsetAsync(ws, 0, (szQ2 + 2*szFS + szR)*sizeof(float), stream);

    k0_wt  <<<dim3(144),      256, 0, stream>>>(wproj, wt);
    k1_qkv <<<dim3(64, 3, 4), 256, 0, stream>>>(x, wqkv, bqkv, Qp2, Kp, Vp);
    k2_ksum<<<dim3(64, 4),    256, 0, stream>>>(Kp, ksum);
    k3_kv  <<<dim3(64, 8, 4), 256, 0, stream>>>(Kp, Vp, kvT2);
    k4_r   <<<dim3(64, 8, 4), 256, 0, stream>>>(Qp2, ksum, rfp);
    k5_attn<<<dim3(64, 8, 4), 512, 0, stream>>>(Qp2, kvT2, rfp, folded);
    k6_conv<<<dim3(128, 4),   256, 0, stream>>>(folded, wt, bproj, out);
}